// Round 3
// baseline (418.883 us; speedup 1.0000x reference)
//
#include <hip/hip_runtime.h>
#include <hip/hip_bf16.h>

// MonarchOutProjection: out[t][r*32+q] = sum_p R[q][r][p] * sum_m L[p][q][m] * x[t][m*32+p]
// Round 3: memory-level parallelism + full residency.
//  - All 16 tile loads batched into regs before conversion (loads in flight together).
//  - 2 tiles per block, grid=1024 -> exactly 4 blocks/CU resident all kernel (no tail).
//  - Tile2 global loads issued mid-tile1 (8 rows after stage1, 8 after stage2 reads):
//    HBM latency hidden behind MFMA/LDS work.
//  - Stage-2 accs packed to bf16 right away: peak VGPR ~110 < 128 (launch_bounds(256,4)).

typedef __attribute__((ext_vector_type(8))) short short8;
typedef __attribute__((ext_vector_type(4))) float floatx4;

__device__ __forceinline__ unsigned int f2bf(float f) {
    unsigned int u = __float_as_uint(f);
    return (u + 0x7fffu + ((u >> 16) & 1u)) >> 16;   // RNE f32->bf16 bits
}
__device__ __forceinline__ unsigned int pack2bf(float a, float b) {
    return f2bf(a) | (f2bf(b) << 16);
}
__device__ __forceinline__ float bf2f(unsigned int u16) {
    return __uint_as_float(u16 << 16);
}

// Lb[(p*2+qt)*64 + lane] (short8) = L[p][q=qt*16+(lane&15)][m=(lane>>4)*8 .. +8] as bf16.
__global__ void prep_weights(const float* __restrict__ L, const float* __restrict__ R,
                             unsigned short* __restrict__ Lb, unsigned short* __restrict__ Rb) {
    const int t = blockIdx.x * 256 + threadIdx.x;          // 0..8191
    const float* src        = (t < 4096) ? L : R;
    unsigned short* dst     = (t < 4096) ? Lb : Rb;
    const int i    = t & 4095;
    const int lane = i & 63;
    const int pq   = i >> 6;
    const int p    = pq >> 1;
    const int qt   = pq & 1;
    const int q    = qt * 16 + (lane & 15);
    const int m0   = (lane >> 4) * 8;
    const float* s = src + (p * 32 + q) * 32 + m0;
    uint4 o;
    o.x = pack2bf(s[0], s[1]);
    o.y = pack2bf(s[2], s[3]);
    o.z = pack2bf(s[4], s[5]);
    o.w = pack2bf(s[6], s[7]);
    *(uint4*)(dst + (size_t)i * 8) = o;
}

__global__ __launch_bounds__(256, 4)
void monarch_kernel(const float* __restrict__ x,
                    const unsigned short* __restrict__ Lb,
                    const unsigned short* __restrict__ Rb,
                    float* __restrict__ out) {
    // Element (t, c) lives at buf[t][c ^ (2*t)]; XOR touches bits 1..4 only, so
    // 32-col groups permute internally and u32 pairs stay contiguous.
    __shared__ __align__(16) unsigned short buf[16][1024];   // 32 KiB -> 5 blocks/CU cap

    const int tid  = threadIdx.x;
    const int w    = tid >> 6;
    const int lane = tid & 63;
    const int tl   = lane & 15;       // token row / MFMA col
    const int quad = lane >> 4;
    const int c    = tid * 4;
    const long tokB = (long)blockIdx.x * 32;   // 2 tiles x 16 tokens

    // ---------- prefetch tile 0: all 16 loads issued before any use ----------
    float4 v[16];
    #pragma unroll
    for (int t = 0; t < 16; ++t)
        v[t] = *(const float4*)(x + (tokB + t) * 1024 + c);

    #pragma unroll 1
    for (int it = 0; it < 2; ++it) {
        const long tok0 = tokB + it * 16;

        // ---------- v -> buf (bf16, swizzled) ----------
        #pragma unroll
        for (int t = 0; t < 16; ++t) {
            *(unsigned int*)&buf[t][(c    ) ^ (2 * t)] = pack2bf(v[t].x, v[t].y);
            *(unsigned int*)&buf[t][(c + 2) ^ (2 * t)] = pack2bf(v[t].z, v[t].w);
        }
        __syncthreads();

        // ---------- stage 1, in place: per p (wave-partitioned): D[q][t] = L[p] * X_p ----
        // Per lane: read cols {m*32+pX} then write cols {q*32+pX}, same set, own row tl.
        {
            const int xsw = 2 * tl;
            #pragma unroll
            for (int pp = 0; pp < 8; ++pp) {
                const int p  = w * 8 + pp;
                const int pX = p ^ xsw;
                short8 b1;
                #pragma unroll
                for (int j = 0; j < 8; ++j)
                    b1[j] = (short)buf[tl][quad * 256 + j * 32 + pX];
                #pragma unroll
                for (int qt = 0; qt < 2; ++qt) {
                    const short8 a1 = *(const short8*)(Lb + (size_t)((p * 2 + qt) * 64 + lane) * 8);
                    floatx4 acc = {0.f, 0.f, 0.f, 0.f};
                    acc = __builtin_amdgcn_mfma_f32_16x16x32_bf16(a1, b1, acc, 0, 0, 0);
                    #pragma unroll
                    for (int r = 0; r < 4; ++r) {
                        const int qo = qt * 16 + quad * 4 + r;
                        buf[tl][qo * 32 + pX] = (unsigned short)f2bf(acc[r]);
                    }
                }
            }
        }
        __syncthreads();

        // ---------- prefetch next tile, first half (overlaps stage 2) ----------
        if (it == 0) {
            #pragma unroll
            for (int t = 0; t < 8; ++t)
                v[t] = *(const float4*)(x + (tokB + 16 + t) * 1024 + c);
        }

        // ---------- stage 2: per q (wave-partitioned): D[r][t] = R[q] * Y1_q ----------
        unsigned int y2p[8][2][2];    // packed bf16 accs: 32 VGPRs
        {
            const int xsw = 2 * tl;
            #pragma unroll
            for (int qq = 0; qq < 8; ++qq) {
                const int q = w * 8 + qq;
                short8 b2;
                #pragma unroll
                for (int j = 0; j < 8; ++j)
                    b2[j] = (short)buf[tl][q * 32 + ((quad * 8 + j) ^ xsw)];
                #pragma unroll
                for (int rt = 0; rt < 2; ++rt) {
                    const short8 a2 = *(const short8*)(Rb + (size_t)((q * 2 + rt) * 64 + lane) * 8);
                    floatx4 z = {0.f, 0.f, 0.f, 0.f};
                    floatx4 acc = __builtin_amdgcn_mfma_f32_16x16x32_bf16(a2, b2, z, 0, 0, 0);
                    y2p[qq][rt][0] = pack2bf(acc[0], acc[1]);
                    y2p[qq][rt][1] = pack2bf(acc[2], acc[3]);
                }
            }
        }

        // ---------- prefetch next tile, second half ----------
        if (it == 0) {
            #pragma unroll
            for (int t = 8; t < 16; ++t)
                v[t] = *(const float4*)(x + (tokB + 16 + t) * 1024 + c);
        }
        __syncthreads();

        // ---------- y2 -> buf ----------
        {
            const int xsw = 2 * tl;
            #pragma unroll
            for (int qq = 0; qq < 8; ++qq) {
                const int q  = w * 8 + qq;
                const int qX = q ^ xsw;
                #pragma unroll
                for (int rt = 0; rt < 2; ++rt) {
                    const int ro = rt * 16 + quad * 4;
                    buf[tl][(ro    ) * 32 + qX] = (unsigned short)(y2p[qq][rt][0] & 0xffffu);
                    buf[tl][(ro + 1) * 32 + qX] = (unsigned short)(y2p[qq][rt][0] >> 16);
                    buf[tl][(ro + 2) * 32 + qX] = (unsigned short)(y2p[qq][rt][1] & 0xffffu);
                    buf[tl][(ro + 3) * 32 + qX] = (unsigned short)(y2p[qq][rt][1] >> 16);
                }
            }
        }
        __syncthreads();

        // ---------- dump: buf -> out, coalesced float4 ----------
        #pragma unroll
        for (int t = 0; t < 16; ++t) {
            const unsigned int u0 = *(const unsigned int*)&buf[t][(c    ) ^ (2 * t)];
            const unsigned int u1 = *(const unsigned int*)&buf[t][(c + 2) ^ (2 * t)];
            float4 o;
            o.x = bf2f(u0 & 0xffffu); o.y = bf2f(u0 >> 16);
            o.z = bf2f(u1 & 0xffffu); o.w = bf2f(u1 >> 16);
            *(float4*)(out + (tok0 + t) * 1024 + c) = o;
        }
        __syncthreads();   // guard: next iteration overwrites buf
    }
}

extern "C" void kernel_launch(void* const* d_in, const int* in_sizes, int n_in,
                              void* d_out, int out_size, void* d_ws, size_t ws_size,
                              hipStream_t stream) {
    const float* x = (const float*)d_in[0];   // (8, 4096, 1024) fp32
    const float* L = (const float*)d_in[1];   // (32, 32, 32) fp32
    const float* R = (const float*)d_in[2];   // (32, 32, 32) fp32
    float* out = (float*)d_out;

    unsigned short* Lb = (unsigned short*)d_ws;          // 32768 bf16 = 64 KiB
    unsigned short* Rb = Lb + 32768;                     // 64 KiB

    prep_weights<<<32, 256, 0, stream>>>(L, R, Lb, Rb);

    const int grid = 1024;                               // 2 tiles x 16 tokens each
    monarch_kernel<<<grid, 256, 0, stream>>>(x, Lb, Rb, out);
}